// Round 5
// baseline (133.147 us; speedup 1.0000x reference)
//
#include <hip/hip_runtime.h>
#include <hip/hip_bf16.h>

#define SEQ   28
#define BATCH 8192
#define NIN   28
#define HID   128
#define NOUT  10

// gate pre-scales folded into weights/bias at pack time:
// i,f,o rows scaled by -log2(e)  -> exp2(z) = e^{-x}  (sigmoid denom)
// g rows scaled by +2*log2(e)    -> exp2(z) = e^{2x}  (tanh)
#define SCL_SIG  (-1.4426950408889634f)
#define SCL_TANH (2.8853900817779268f)

typedef __bf16 bf16_t;
typedef __bf16 bf16x8 __attribute__((ext_vector_type(8)));
typedef float  f32x4  __attribute__((ext_vector_type(4)));

// XOR-swizzle for row-major [rows][128] bf16 tiles (256B rows).
__device__ __forceinline__ unsigned swz(unsigned row, unsigned byte_in_row) {
    return row * 256u + (byte_in_row ^ ((row & 7u) << 4));
}

// Per-step barrier: LDS-only drain. __syncthreads() would emit vmcnt(0) too,
// force-draining the x prefetch loads + h1 stores every step (the m97 stall).
// Cross-wave traffic inside a step is LDS-only, so lgkmcnt(0) suffices.
__device__ __forceinline__ void barrier_lds() {
    asm volatile("s_waitcnt lgkmcnt(0)\n\ts_barrier" ::: "memory");
}

// Pack {Whh0, Whh1, Wih1} [512][128] fp32 -> frag-linear bf16 with per-gate
// scaling. frag index (ks*32+nt)*64+lane, elem j: gate = nt*16+(lane&15),
// k = ks*32+(lane>>4)*8+j.
__global__ void pack_w_kernel(const float* __restrict__ Whh0, bf16_t* __restrict__ o0,
                              const float* __restrict__ Whh1, bf16_t* __restrict__ o1,
                              const float* __restrict__ Wih1, bf16_t* __restrict__ o2) {
    int idx = blockIdx.x * 256 + threadIdx.x;      // 0 .. 3*65536-1
    int mi = idx >> 16;
    int e  = idx & 65535;
    const float* W = (mi == 0) ? Whh0 : (mi == 1) ? Whh1 : Wih1;
    bf16_t*      o = (mi == 0) ? o0   : (mi == 1) ? o1   : o2;
    int j    = e & 7;
    int frag = e >> 3;
    int lane = frag & 63;
    int ksnt = frag >> 6;
    int nt = ksnt & 31, ks = ksnt >> 5;
    int gate = nt * 16 + (lane & 15);
    int k    = ks * 32 + ((lane >> 4) << 3) + j;
    float s  = ((gate >> 7) == 2) ? SCL_TANH : SCL_SIG;
    o[e] = (bf16_t)(W[gate * 128 + k] * s);
}

// Load one L0 x A-frag (fp32 X row, K padded 28->32) into bf16x8.
__device__ __forceinline__ bf16x8 load_x0(const float* __restrict__ X,
                                          int t, int rb, int m, int l15, int l4) {
    const float* base = X + ((size_t)(t * BATCH + rb + 16 * m + l15)) * NIN + l4 * 8;
    f32x4 lo = *(const f32x4*)base;
    f32x4 hi = {0.f, 0.f, 0.f, 0.f};
    if (l4 < 3) hi = *(const f32x4*)(base + 4);
    bf16x8 v;
    #pragma unroll
    for (int j = 0; j < 4; ++j) { v[j] = (bf16_t)lo[j]; v[4 + j] = (bf16_t)hi[j]; }
    return v;
}

// One LSTM step. Wave w owns N-tiles {w, w+8, w+16, w+24} = gates i,f,g,o
// (pre-scaled) for h-columns [16w,16w+16). Consumes xc; issues the load of
// timestep `tload` into xl (L0: xl==xc, tload=t+2 (depth-2); L1: xl==xc,
// tload=t+1 (depth-1, h1 is L2-warm)).
template <int LAYER>
__device__ __forceinline__ void lstm_step(
    int t, int tload, int rb, int tid, int lane, int w, int l15, int l4,
    unsigned char* smem,
    const float* __restrict__ X, const bf16_t* __restrict__ h1r,
    bf16_t* __restrict__ h1w,
    bf16x8 (&whh)[4][4], bf16x8 (&wih)[4][4],
    float (&bias)[4], float (&c)[2][4],
    bf16x8 (&xc)[4][2], bf16x8 (&xl)[4][2])
{
    constexpr int KS = (LAYER == 0) ? 1 : 4;
    unsigned char* hb = smem + ((t & 1) << 13);
    unsigned char* hn = smem + ((~t & 1) << 13);

    // ---- h a-frags (all 8 ds_reads up front) ----
    bf16x8 ah[4][2];
    #pragma unroll
    for (int ks = 0; ks < 4; ++ks)
        #pragma unroll
        for (int m = 0; m < 2; ++m)
            ah[ks][m] = *(const bf16x8*)(hb + swz(16 * m + l15, (ks * 32 + l4 * 8) * 2));

    f32x4 acc[2][4];
    #pragma unroll
    for (int m = 0; m < 2; ++m)
        #pragma unroll
        for (int q = 0; q < 4; ++q) {
            f32x4 b = {bias[q], bias[q], bias[q], bias[q]};
            acc[m][q] = b;
        }

    // ---- x-part MFMAs (operands in registers, prefetched earlier) ----
    #pragma unroll
    for (int m = 0; m < 2; ++m)
        #pragma unroll
        for (int q = 0; q < 4; ++q)
            #pragma unroll
            for (int ks = 0; ks < KS; ++ks)
                acc[m][q] = __builtin_amdgcn_mfma_f32_16x16x32_bf16(
                    xc[ks][m], wih[q][ks], acc[m][q], 0, 0, 0);

    // ---- issue x load for t=tload (latency hides under rest of step) ----
    if (tload < SEQ) {
        if constexpr (LAYER == 0) {
            #pragma unroll
            for (int m = 0; m < 2; ++m)
                xl[0][m] = load_x0(X, tload, rb, m, l15, l4);
        } else {
            #pragma unroll
            for (int ks = 0; ks < 4; ++ks)
                #pragma unroll
                for (int m = 0; m < 2; ++m)
                    xl[ks][m] = *(const bf16x8*)(h1r + ((size_t)(tload * BATCH + rb + 16 * m + l15)) * HID + ks * 32 + l4 * 8);
        }
    }

    // ---- h-part MFMAs ----
    #pragma unroll
    for (int m = 0; m < 2; ++m)
        #pragma unroll
        for (int q = 0; q < 4; ++q)
            #pragma unroll
            for (int ks = 0; ks < 4; ++ks)
                acc[m][q] = __builtin_amdgcn_mfma_f32_16x16x32_bf16(
                    ah[ks][m], whh[q][ks], acc[m][q], 0, 0, 0);

    // ---- activations: 5 exp2 + 2 rcp per element ----
    // cn = f*c + i*g = (c*ti*tg + tf*(tg-2)) / (tf*ti*tg)
    // h  = o*tanh(cn) = (Ec-1) / (to*(1+Ec)),  Ec = e^{2cn}
    #pragma unroll
    for (int m = 0; m < 2; ++m)
        #pragma unroll
        for (int r = 0; r < 4; ++r) {
            float Ei = __builtin_amdgcn_exp2f(acc[m][0][r]);   // e^{-zi}
            float Ef = __builtin_amdgcn_exp2f(acc[m][1][r]);   // e^{-zf}
            float Eg = __builtin_amdgcn_exp2f(acc[m][2][r]);   // e^{2zg}
            float Eo = __builtin_amdgcn_exp2f(acc[m][3][r]);   // e^{-zo}
            float ti = 1.0f + Ei, tf = 1.0f + Ef;
            float tg = 1.0f + Eg, to = 1.0f + Eo;
            float titg = ti * tg;
            float num  = fmaf(c[m][r], titg, tf * (tg - 2.0f));
            float cn   = num * __builtin_amdgcn_rcpf(tf * titg);
            c[m][r] = cn;
            float Ec = __builtin_amdgcn_exp2f(SCL_TANH * cn);  // e^{2cn}
            float hv = (Ec - 1.0f) * __builtin_amdgcn_rcpf(to * (1.0f + Ec));
            *(bf16_t*)(hn + swz(16 * m + l4 * 4 + r, (16 * w + l15) * 2)) = (bf16_t)hv;
        }
    barrier_lds();

    // ---- L0: stream h_t to global h1 (coalesced 16B) ----
    if constexpr (LAYER == 0) {
        int row = tid >> 4, sc = tid & 15;
        f32x4 v = *(const f32x4*)(hn + swz(row, sc * 16));
        *(f32x4*)((unsigned char*)h1w + ((size_t)(t * BATCH + rb + row)) * 256 + sc * 16) = v;
    }
}

// Fused 2-layer LSTM: one block = 32 batch rows through BOTH layers.
// 8 waves, 1 block/CU. Weights register-resident (frag-linear preload).
__global__ __launch_bounds__(512, 2)
void lstm_fused_kernel(const float* __restrict__ Wih0,
                       const float* __restrict__ bih0, const float* __restrict__ bhh0,
                       const float* __restrict__ bih1, const float* __restrict__ bhh1,
                       const float* __restrict__ X,
                       const bf16_t* __restrict__ whhp0,
                       const bf16_t* __restrict__ whhp1,
                       const bf16_t* __restrict__ wihp1,
                       bf16_t* __restrict__ h1,
                       const float* __restrict__ Wlin, const float* __restrict__ blin,
                       float* __restrict__ out)
{
    __shared__ unsigned char smem[16384] __attribute__((aligned(16)));

    const int tid  = threadIdx.x;
    const int lane = tid & 63;
    const int w    = tid >> 6;
    const int l15  = lane & 15;
    const int l4   = lane >> 4;
    const int rb   = blockIdx.x * 32;

    bf16x8 whh[4][4], wih[4][4];
    float  bias[4];
    float  c[2][4];
    bf16x8 xA[4][2], xB[4][2];

    // ================= phase 0: layer 0 =================
    #pragma unroll
    for (int q = 0; q < 4; ++q)
        #pragma unroll
        for (int ks = 0; ks < 4; ++ks)
            whh[q][ks] = *(const bf16x8*)(whhp0 + ((size_t)((ks * 32 + (w + 8 * q)) * 64 + lane)) * 8);
    #pragma unroll
    for (int q = 0; q < 4; ++q) {
        int gate = 16 * w + 128 * q + l15;
        float s = (q == 2) ? SCL_TANH : SCL_SIG;
        #pragma unroll
        for (int j = 0; j < 8; ++j) {
            int k = l4 * 8 + j;
            wih[q][0][j] = (k < NIN) ? (bf16_t)(Wih0[gate * NIN + k] * s) : (bf16_t)0.0f;
        }
        bias[q] = (bih0[gate] + bhh0[gate]) * s;
        c[0][q] = 0.f; c[1][q] = 0.f;
    }
    // zero h buffers
    for (int i = tid * 16; i < 16384; i += 512 * 16) {
        f32x4 z = {0.f, 0.f, 0.f, 0.f};
        *(f32x4*)(smem + i) = z;
    }
    // x(t=0) -> xA, x(t=1) -> xB (depth-2 pipeline prologue)
    #pragma unroll
    for (int m = 0; m < 2; ++m) {
        xA[0][m] = load_x0(X, 0, rb, m, l15, l4);
        xB[0][m] = load_x0(X, 1, rb, m, l15, l4);
    }
    __syncthreads();

    for (int t = 0; t < SEQ; t += 2) {
        lstm_step<0>(t,     t + 2, rb, tid, lane, w, l15, l4, smem, X, nullptr, h1,
                     whh, wih, bias, c, xA, xA);
        lstm_step<0>(t + 1, t + 3, rb, tid, lane, w, l15, l4, smem, X, nullptr, h1,
                     whh, wih, bias, c, xB, xB);
    }

    __syncthreads();   // full drain: h1 global stores visible to all waves

    // ================= phase 1: layer 1 =================
    #pragma unroll
    for (int q = 0; q < 4; ++q) {
        #pragma unroll
        for (int ks = 0; ks < 4; ++ks) {
            whh[q][ks] = *(const bf16x8*)(whhp1 + ((size_t)((ks * 32 + (w + 8 * q)) * 64 + lane)) * 8);
            wih[q][ks] = *(const bf16x8*)(wihp1 + ((size_t)((ks * 32 + (w + 8 * q)) * 64 + lane)) * 8);
        }
        int gate = 16 * w + 128 * q + l15;
        float s = (q == 2) ? SCL_TANH : SCL_SIG;
        bias[q] = (bih1[gate] + bhh1[gate]) * s;
        c[0][q] = 0.f; c[1][q] = 0.f;
    }
    for (int i = tid * 16; i < 16384; i += 512 * 16) {
        f32x4 z = {0.f, 0.f, 0.f, 0.f};
        *(f32x4*)(smem + i) = z;
    }
    // x(t=0) from h1
    #pragma unroll
    for (int ks = 0; ks < 4; ++ks)
        #pragma unroll
        for (int m = 0; m < 2; ++m)
            xA[ks][m] = *(const bf16x8*)(h1 + ((size_t)(rb + 16 * m + l15)) * HID + ks * 32 + l4 * 8);
    __syncthreads();

    for (int t = 0; t < SEQ; ++t)
        lstm_step<1>(t, t + 1, rb, tid, lane, w, l15, l4, smem, nullptr, h1, nullptr,
                     whh, wih, bias, c, xA, xA);

    // ---- epilogue: pred = h2[27] @ W_lin^T + b_lin (t=27 wrote buf0) ----
    if (tid < 32 * NOUT) {
        int row = tid / NOUT, oc = tid % NOUT;
        const unsigned char* hf = smem;   // buffer 0
        float s = blin[oc];
        #pragma unroll 8
        for (int k = 0; k < HID; ++k) {
            float h = (float)*(const bf16_t*)(hf + swz(row, k * 2));
            s += h * Wlin[oc * HID + k];
        }
        out[(size_t)(rb + row) * NOUT + oc] = s;
    }
}

extern "C" void kernel_launch(void* const* d_in, const int* in_sizes, int n_in,
                              void* d_out, int out_size, void* d_ws, size_t ws_size,
                              hipStream_t stream) {
    const float* X    = (const float*)d_in[0];
    const float* Wih0 = (const float*)d_in[1];
    const float* Whh0 = (const float*)d_in[2];
    const float* bih0 = (const float*)d_in[3];
    const float* bhh0 = (const float*)d_in[4];
    const float* Wih1 = (const float*)d_in[5];
    const float* Whh1 = (const float*)d_in[6];
    const float* bih1 = (const float*)d_in[7];
    const float* bhh1 = (const float*)d_in[8];
    const float* Wlin = (const float*)d_in[9];
    const float* blin = (const float*)d_in[10];
    float* out = (float*)d_out;

    unsigned char* ws = (unsigned char*)d_ws;
    bf16_t* h1    = (bf16_t*)(ws);                       // 58,720,256 B
    bf16_t* whhp0 = (bf16_t*)(ws + 58720256);            //    131,072 B
    bf16_t* whhp1 = (bf16_t*)(ws + 58851328);            //    131,072 B
    bf16_t* wihp1 = (bf16_t*)(ws + 58982400);            //    131,072 B

    pack_w_kernel<<<dim3(768), dim3(256), 0, stream>>>(Whh0, whhp0, Whh1, whhp1, Wih1, wihp1);

    lstm_fused_kernel<<<dim3(256), dim3(512), 0, stream>>>(
        Wih0, bih0, bhh0, bih1, bhh1, X, whhp0, whhp1, wihp1, h1,
        Wlin, blin, out);
}

// Round 6
// 120.613 us; speedup vs baseline: 1.1039x; 1.1039x over previous
//
#include <hip/hip_runtime.h>
#include <hip/hip_bf16.h>

#define SEQ   28
#define BATCH 8192
#define NIN   28
#define HID   128
#define NOUT  10

// gate pre-scales folded into weights/bias at pack time:
// i,f,o rows scaled by -log2(e)  -> exp2(z) = e^{-x}  (sigmoid denom)
// g rows scaled by +2*log2(e)    -> exp2(z) = e^{2x}  (tanh)
#define SCL_SIG  (-1.4426950408889634f)
#define SCL_TANH (2.8853900817779268f)

typedef __bf16 bf16_t;
typedef __bf16 bf16x8 __attribute__((ext_vector_type(8)));
typedef float  f32x4  __attribute__((ext_vector_type(4)));

// XOR-swizzle for row-major [rows][128] bf16 tiles (256B rows).
__device__ __forceinline__ unsigned swz(unsigned row, unsigned byte_in_row) {
    return row * 256u + (byte_in_row ^ ((row & 7u) << 4));
}

// Per-step barrier: LDS-only drain (cross-wave traffic inside a step is LDS).
__device__ __forceinline__ void barrier_lds() {
    asm volatile("s_waitcnt lgkmcnt(0)\n\ts_barrier" ::: "memory");
}

// Pack {Whh0, Whh1, Wih1} [512][128] fp32 -> frag-linear bf16 with per-gate
// scaling. frag index (ks*32+nt)*64+lane, elem j: gate = nt*16+(lane&15),
// k = ks*32+(lane>>4)*8+j.
__global__ void pack_w_kernel(const float* __restrict__ Whh0, bf16_t* __restrict__ o0,
                              const float* __restrict__ Whh1, bf16_t* __restrict__ o1,
                              const float* __restrict__ Wih1, bf16_t* __restrict__ o2) {
    int idx = blockIdx.x * 256 + threadIdx.x;      // 0 .. 3*65536-1
    int mi = idx >> 16;
    int e  = idx & 65535;
    const float* W = (mi == 0) ? Whh0 : (mi == 1) ? Whh1 : Wih1;
    bf16_t*      o = (mi == 0) ? o0   : (mi == 1) ? o1   : o2;
    int j    = e & 7;
    int frag = e >> 3;
    int lane = frag & 63;
    int ksnt = frag >> 6;
    int nt = ksnt & 31, ks = ksnt >> 5;
    int gate = nt * 16 + (lane & 15);
    int k    = ks * 32 + ((lane >> 4) << 3) + j;
    float s  = ((gate >> 7) == 2) ? SCL_TANH : SCL_SIG;
    o[e] = (bf16_t)(W[gate * 128 + k] * s);
}

// Load one L0 x A-frag (fp32 X row, K padded 28->32) into bf16x8.
__device__ __forceinline__ bf16x8 load_x0(const float* __restrict__ X,
                                          int t, int rb, int m, int l15, int l4) {
    const float* base = X + ((size_t)(t * BATCH + rb + 16 * m + l15)) * NIN + l4 * 8;
    f32x4 lo = *(const f32x4*)base;
    f32x4 hi = {0.f, 0.f, 0.f, 0.f};
    if (l4 < 3) hi = *(const f32x4*)(base + 4);
    bf16x8 v;
    #pragma unroll
    for (int j = 0; j < 4; ++j) { v[j] = (bf16_t)lo[j]; v[4 + j] = (bf16_t)hi[j]; }
    return v;
}

// One LSTM step, overlap-structured:
//   barrier; [L0: stream h(t-1)->h1]; ds_read h(t-1); h-MFMA into accIn;
//   per m-slice: {trans(t) from accIn[m]  ||  x-MFMA(t+1) into accOut[m]};
//   issue x(t+2) loads.
// accIn enters holding bias + x(t)-part; accOut leaves holding bias +
// x(t+1)-part. The x-part MFMAs and x loads are independent of h(t), so the
// scheduler can fill the MFMA pipe during the trans phase (m-sliced so
// accIn[m] register lifetime ends exactly as accOut[m] begins).
template <int LAYER>
__device__ __forceinline__ void step_v2(
    int t, int rb, int tid, int w, int l15, int l4,
    unsigned char* smem,
    const float* __restrict__ X, const bf16_t* __restrict__ h1r,
    bf16_t* __restrict__ h1w,
    bf16x8 (&whh)[4][4], bf16x8 (&wih)[4][4],
    float (&bias)[4], float (&c)[2][4],
    bf16x8 (&x)[4][2],
    f32x4 (&accIn)[2][4], f32x4 (&accOut)[2][4])
{
    constexpr int KS = (LAYER == 0) ? 1 : 4;
    unsigned char* hb = smem + ((~t & 1) << 13);   // holds h(t-1)
    unsigned char* hn = smem + ((t & 1) << 13);    // receives h(t)

    barrier_lds();   // all waves' h(t-1) LDS writes complete & visible

    // ---- L0: stream h(t-1) to global h1 (reads hb, now consistent) ----
    if constexpr (LAYER == 0) {
        if (t >= 1) {
            int row = tid >> 4, sc = tid & 15;
            f32x4 v = *(const f32x4*)(hb + swz(row, sc * 16));
            *(f32x4*)((unsigned char*)h1w + ((size_t)((t - 1) * BATCH + rb + row)) * 256 + sc * 16) = v;
        }
    }

    // ---- h-part MFMAs (ks-chunked: 4 a-frags live at a time) ----
    #pragma unroll
    for (int kc = 0; kc < 2; ++kc) {
        bf16x8 a0[2], a1[2];
        #pragma unroll
        for (int m = 0; m < 2; ++m) {
            a0[m] = *(const bf16x8*)(hb + swz(16 * m + l15, ((2 * kc) * 32 + l4 * 8) * 2));
            a1[m] = *(const bf16x8*)(hb + swz(16 * m + l15, ((2 * kc + 1) * 32 + l4 * 8) * 2));
        }
        #pragma unroll
        for (int m = 0; m < 2; ++m)
            #pragma unroll
            for (int q = 0; q < 4; ++q) {
                accIn[m][q] = __builtin_amdgcn_mfma_f32_16x16x32_bf16(
                    a0[m], whh[q][2 * kc], accIn[m][q], 0, 0, 0);
                accIn[m][q] = __builtin_amdgcn_mfma_f32_16x16x32_bf16(
                    a1[m], whh[q][2 * kc + 1], accIn[m][q], 0, 0, 0);
            }
    }

    // ---- per m-slice: activations(t) || x-part MFMAs for t+1 ----
    #pragma unroll
    for (int m = 0; m < 2; ++m) {
        // activations: 5 exp2 + 2 rcp per element
        #pragma unroll
        for (int r = 0; r < 4; ++r) {
            float Ei = __builtin_amdgcn_exp2f(accIn[m][0][r]);   // e^{-zi}
            float Ef = __builtin_amdgcn_exp2f(accIn[m][1][r]);   // e^{-zf}
            float Eg = __builtin_amdgcn_exp2f(accIn[m][2][r]);   // e^{2zg}
            float Eo = __builtin_amdgcn_exp2f(accIn[m][3][r]);   // e^{-zo}
            float ti = 1.0f + Ei, tf = 1.0f + Ef;
            float tg = 1.0f + Eg, to = 1.0f + Eo;
            float titg = ti * tg;
            float num  = fmaf(c[m][r], titg, tf * (tg - 2.0f));
            float cn   = num * __builtin_amdgcn_rcpf(tf * titg);
            c[m][r] = cn;
            float Ec = __builtin_amdgcn_exp2f(SCL_TANH * cn);    // e^{2cn}
            float hv = (Ec - 1.0f) * __builtin_amdgcn_rcpf(to * (1.0f + Ec));
            *(bf16_t*)(hn + swz(16 * m + l4 * 4 + r, (16 * w + l15) * 2)) = (bf16_t)hv;
        }
        // x-part MFMAs for t+1 (independent of h(t); consumes x(t+1) regs)
        #pragma unroll
        for (int q = 0; q < 4; ++q) {
            f32x4 b = {bias[q], bias[q], bias[q], bias[q]};
            accOut[m][q] = b;
            #pragma unroll
            for (int ks = 0; ks < KS; ++ks)
                accOut[m][q] = __builtin_amdgcn_mfma_f32_16x16x32_bf16(
                    x[ks][m], wih[q][ks], accOut[m][q], 0, 0, 0);
        }
    }

    // ---- issue x(t+2) loads into the just-freed x regs ----
    if (t + 2 < SEQ) {
        if constexpr (LAYER == 0) {
            #pragma unroll
            for (int m = 0; m < 2; ++m)
                x[0][m] = load_x0(X, t + 2, rb, m, l15, l4);
        } else {
            #pragma unroll
            for (int ks = 0; ks < 4; ++ks)
                #pragma unroll
                for (int m = 0; m < 2; ++m)
                    x[ks][m] = *(const bf16x8*)(h1r + ((size_t)((t + 2) * BATCH + rb + 16 * m + l15)) * HID + ks * 32 + l4 * 8);
        }
    }
}

// Fused 2-layer LSTM: one block = 32 batch rows through BOTH layers.
// 8 waves, 1 block/CU. Weights register-resident (frag-linear preload).
__global__ __launch_bounds__(512, 2)
void lstm_fused_kernel(const float* __restrict__ Wih0,
                       const float* __restrict__ bih0, const float* __restrict__ bhh0,
                       const float* __restrict__ bih1, const float* __restrict__ bhh1,
                       const float* __restrict__ X,
                       const bf16_t* __restrict__ whhp0,
                       const bf16_t* __restrict__ whhp1,
                       const bf16_t* __restrict__ wihp1,
                       bf16_t* __restrict__ h1,
                       const float* __restrict__ Wlin, const float* __restrict__ blin,
                       float* __restrict__ out)
{
    __shared__ unsigned char smem[16384] __attribute__((aligned(16)));

    const int tid  = threadIdx.x;
    const int lane = tid & 63;
    const int w    = tid >> 6;
    const int l15  = lane & 15;
    const int l4   = lane >> 4;
    const int rb   = blockIdx.x * 32;

    bf16x8 whh[4][4], wih[4][4];
    float  bias[4];
    float  c[2][4];
    bf16x8 x[4][2];
    f32x4  accA[2][4], accB[2][4];

    // ================= phase 0: layer 0 =================
    #pragma unroll
    for (int q = 0; q < 4; ++q)
        #pragma unroll
        for (int ks = 0; ks < 4; ++ks)
            whh[q][ks] = *(const bf16x8*)(whhp0 + ((size_t)((ks * 32 + (w + 8 * q)) * 64 + lane)) * 8);
    #pragma unroll
    for (int q = 0; q < 4; ++q) {
        int gate = 16 * w + 128 * q + l15;
        float s = (q == 2) ? SCL_TANH : SCL_SIG;
        #pragma unroll
        for (int j = 0; j < 8; ++j) {
            int k = l4 * 8 + j;
            wih[q][0][j] = (k < NIN) ? (bf16_t)(Wih0[gate * NIN + k] * s) : (bf16_t)0.0f;
        }
        bias[q] = (bih0[gate] + bhh0[gate]) * s;
        c[0][q] = 0.f; c[1][q] = 0.f;
    }
    // zero both h buffers
    for (int i = tid * 16; i < 16384; i += 512 * 16) {
        f32x4 z = {0.f, 0.f, 0.f, 0.f};
        *(f32x4*)(smem + i) = z;
    }
    // accA = bias + x(0)-part; then prefetch x(1)
    #pragma unroll
    for (int m = 0; m < 2; ++m)
        x[0][m] = load_x0(X, 0, rb, m, l15, l4);
    #pragma unroll
    for (int m = 0; m < 2; ++m)
        #pragma unroll
        for (int q = 0; q < 4; ++q) {
            f32x4 b = {bias[q], bias[q], bias[q], bias[q]};
            accA[m][q] = __builtin_amdgcn_mfma_f32_16x16x32_bf16(
                x[0][m], wih[q][0], b, 0, 0, 0);
        }
    #pragma unroll
    for (int m = 0; m < 2; ++m)
        x[0][m] = load_x0(X, 1, rb, m, l15, l4);
    // body(0)'s top barrier makes the zero-init visible

    for (int t = 0; t < SEQ; t += 2) {
        step_v2<0>(t,     rb, tid, w, l15, l4, smem, X, nullptr, h1,
                   whh, wih, bias, c, x, accA, accB);
        step_v2<0>(t + 1, rb, tid, w, l15, l4, smem, X, nullptr, h1,
                   whh, wih, bias, c, x, accB, accA);
    }

    // final h(27) -> h1, then full drain before phase 1
    barrier_lds();
    {
        int row = tid >> 4, sc = tid & 15;
        f32x4 v = *(const f32x4*)(smem + 8192 + swz(row, sc * 16));  // buf1 = h(27)
        *(f32x4*)((unsigned char*)h1 + ((size_t)(27 * BATCH + rb + row)) * 256 + sc * 16) = v;
    }
    __syncthreads();   // h1 global stores drained (vmcnt) before L1 reads

    // ================= phase 1: layer 1 =================
    #pragma unroll
    for (int q = 0; q < 4; ++q) {
        #pragma unroll
        for (int ks = 0; ks < 4; ++ks) {
            whh[q][ks] = *(const bf16x8*)(whhp1 + ((size_t)((ks * 32 + (w + 8 * q)) * 64 + lane)) * 8);
            wih[q][ks] = *(const bf16x8*)(wihp1 + ((size_t)((ks * 32 + (w + 8 * q)) * 64 + lane)) * 8);
        }
        int gate = 16 * w + 128 * q + l15;
        float s = (q == 2) ? SCL_TANH : SCL_SIG;
        bias[q] = (bih1[gate] + bhh1[gate]) * s;
        c[0][q] = 0.f; c[1][q] = 0.f;
    }
    // re-zero both h buffers (L0 left h-state in them)
    for (int i = tid * 16; i < 16384; i += 512 * 16) {
        f32x4 z = {0.f, 0.f, 0.f, 0.f};
        *(f32x4*)(smem + i) = z;
    }
    // accA = bias + x(0)-part from h1; then prefetch x(1)
    #pragma unroll
    for (int ks = 0; ks < 4; ++ks)
        #pragma unroll
        for (int m = 0; m < 2; ++m)
            x[ks][m] = *(const bf16x8*)(h1 + ((size_t)(rb + 16 * m + l15)) * HID + ks * 32 + l4 * 8);
    #pragma unroll
    for (int m = 0; m < 2; ++m)
        #pragma unroll
        for (int q = 0; q < 4; ++q) {
            f32x4 b = {bias[q], bias[q], bias[q], bias[q]};
            accA[m][q] = b;
            #pragma unroll
            for (int ks = 0; ks < 4; ++ks)
                accA[m][q] = __builtin_amdgcn_mfma_f32_16x16x32_bf16(
                    x[ks][m], wih[q][ks], accA[m][q], 0, 0, 0);
        }
    #pragma unroll
    for (int ks = 0; ks < 4; ++ks)
        #pragma unroll
        for (int m = 0; m < 2; ++m)
            x[ks][m] = *(const bf16x8*)(h1 + ((size_t)(BATCH + rb + 16 * m + l15)) * HID + ks * 32 + l4 * 8);
    // body(0)'s top barrier makes the re-zero visible

    for (int t = 0; t < SEQ; t += 2) {
        step_v2<1>(t,     rb, tid, w, l15, l4, smem, nullptr, h1, nullptr,
                   whh, wih, bias, c, x, accA, accB);
        step_v2<1>(t + 1, rb, tid, w, l15, l4, smem, nullptr, h1, nullptr,
                   whh, wih, bias, c, x, accB, accA);
    }
    barrier_lds();   // h2(27) in buf1 consistent

    // ---- epilogue: pred = h2[27] @ W_lin^T + b_lin ----
    if (tid < 32 * NOUT) {
        int row = tid / NOUT, oc = tid % NOUT;
        const unsigned char* hf = smem + 8192;   // buf1 = h2(27)
        float s = blin[oc];
        #pragma unroll 8
        for (int k = 0; k < HID; ++k) {
            float h = (float)*(const bf16_t*)(hf + swz(row, k * 2));
            s += h * Wlin[oc * HID + k];
        }
        out[(size_t)(rb + row) * NOUT + oc] = s;
    }
}

extern "C" void kernel_launch(void* const* d_in, const int* in_sizes, int n_in,
                              void* d_out, int out_size, void* d_ws, size_t ws_size,
                              hipStream_t stream) {
    const float* X    = (const float*)d_in[0];
    const float* Wih0 = (const float*)d_in[1];
    const float* Whh0 = (const float*)d_in[2];
    const float* bih0 = (const float*)d_in[3];
    const float* bhh0 = (const float*)d_in[4];
    const float* Wih1 = (const float*)d_in[5];
    const float* Whh1 = (const float*)d_in[6];
    const float* bih1 = (const float*)d_in[7];
    const float* bhh1 = (const float*)d_in[8];
    const float* Wlin = (const float*)d_in[9];
    const float* blin = (const float*)d_in[10];
    float* out = (float*)d_out;

    unsigned char* ws = (unsigned char*)d_ws;
    bf16_t* h1    = (bf16_t*)(ws);                       // 58,720,256 B
    bf16_t* whhp0 = (bf16_t*)(ws + 58720256);            //    131,072 B
    bf16_t* whhp1 = (bf16_t*)(ws + 58851328);            //    131,072 B
    bf16_t* wihp1 = (bf16_t*)(ws + 58982400);            //    131,072 B

    pack_w_kernel<<<dim3(768), dim3(256), 0, stream>>>(Whh0, whhp0, Whh1, whhp1, Wih1, wihp1);

    lstm_fused_kernel<<<dim3(256), dim3(512), 0, stream>>>(
        Wih0, bih0, bhh0, bih1, bhh1, X, whhp0, whhp1, wihp1, h1,
        Wlin, blin, out);
}